// Round 5
// baseline (147.490 us; speedup 1.0000x reference)
//
#include <hip/hip_runtime.h>

// MultiHeadAttention: B=2, T=S=2048, D=512, H=8, HS=64
// prep (weight transpose + q/k/v f32->fp16) -> proj3 (128x128 MFMA GEMMs)
//   -> attn (flash, 32q/wave, swapped-QK, static-max exp2(s-12), ones-MFMA rowsum)
//   -> final GEMM 128x128 (+bias, f32 out).
// ws (26MB): Wqt|Wkt|Wvt|Pt (512KB ea) | Qh|Kh|Vh fp16 (4MB ea; Oa reuses Qh) | Qp|Kp|Vt (4MB ea)

typedef float    fx4 __attribute__((ext_vector_type(4)));
typedef _Float16 h8v __attribute__((ext_vector_type(8)));
typedef __fp16   fp16x2 __attribute__((ext_vector_type(2)));
typedef _Float16 h4v __attribute__((ext_vector_type(4)));

#define LOG2E 1.4426950408889634f

typedef const __attribute__((address_space(1))) void* gptr_t;
typedef __attribute__((address_space(3))) void* lptr_t;
__device__ __forceinline__ void gload16(const void* g, void* l) {
    __builtin_amdgcn_global_load_lds((gptr_t)g, (lptr_t)l, 16, 0, 0);
}
#define VMCNT(n) asm volatile("s_waitcnt vmcnt(" #n ")" ::: "memory")
#define LGKMCNT0 asm volatile("s_waitcnt lgkmcnt(0)" ::: "memory")

// ---------------- prep: y=0..2 convert q/k/v to fp16; y=3..6 transpose weights
__global__ __launch_bounds__(256) void prep_kernel(
    const float* __restrict__ q, const float* __restrict__ k, const float* __restrict__ v,
    const float* __restrict__ wq, const float* __restrict__ wk,
    const float* __restrict__ wv, const float* __restrict__ wp,
    _Float16* __restrict__ Qh, _Float16* __restrict__ Kh, _Float16* __restrict__ Vh,
    _Float16* __restrict__ Wqt, _Float16* __restrict__ Wkt,
    _Float16* __restrict__ Wvt, _Float16* __restrict__ Pt)
{
    __shared__ float tile[64 * 65];
    int y = blockIdx.y;
    if (y < 3) {
        const float* src = y == 0 ? q : y == 1 ? k : v;
        _Float16* dst = y == 0 ? Qh : y == 1 ? Kh : Vh;
        int i = (blockIdx.x * 256 + threadIdx.x) * 8;   // 4096*512 elems, grid.x=1024
        float4 f0 = *(const float4*)(src + i);
        float4 f1 = *(const float4*)(src + i + 4);
        h8v hv;
        hv[0] = (_Float16)f0.x; hv[1] = (_Float16)f0.y;
        hv[2] = (_Float16)f0.z; hv[3] = (_Float16)f0.w;
        hv[4] = (_Float16)f1.x; hv[5] = (_Float16)f1.y;
        hv[6] = (_Float16)f1.z; hv[7] = (_Float16)f1.w;
        *(h8v*)(dst + i) = hv;
        return;
    }
    if (blockIdx.x >= 64) return;
    int w = y - 3;
    const float* in = w == 0 ? wq : w == 1 ? wk : w == 2 ? wv : wp;
    _Float16* out = w == 0 ? Wqt : w == 1 ? Wkt : w == 2 ? Wvt : Pt;
    float scale = (w == 0) ? 0.125f * LOG2E : 1.0f;
    const float* src; _Float16* obase; int R0, SI;
    if (w < 3) {                       // [8h][512][64] -> [8h][64][512]
        int h = blockIdx.x >> 3, kt = blockIdx.x & 7;
        src = in + h * 32768 + (kt * 64) * 64; SI = 64;
        obase = out + h * 32768; R0 = kt * 64;
    } else {                           // [512][512] -> [512][512]^T
        int rt = blockIdx.x >> 3, ct = blockIdx.x & 7;
        src = in + (rt * 64) * 512 + ct * 64; SI = 512;
        obase = out + (ct * 64) * 512; R0 = rt * 64;
    }
    int t = threadIdx.x;
    int r = t >> 4, c4 = (t & 15) << 2;
    #pragma unroll
    for (int p = 0; p < 4; ++p) {
        float4 f = *(const float4*)(src + (r + p * 16) * SI + c4);
        tile[(c4 + 0) * 65 + r + p * 16] = f.x;
        tile[(c4 + 1) * 65 + r + p * 16] = f.y;
        tile[(c4 + 2) * 65 + r + p * 16] = f.z;
        tile[(c4 + 3) * 65 + r + p * 16] = f.w;
    }
    __syncthreads();
    int c = t >> 2, seg = (t & 3) << 4;
    h8v h0, h1;
    #pragma unroll
    for (int j = 0; j < 8; ++j) {
        h0[j] = (_Float16)(tile[c * 65 + seg + j] * scale);
        h1[j] = (_Float16)(tile[c * 65 + seg + 8 + j] * scale);
    }
    *(h8v*)(obase + c * 512 + R0 + seg) = h0;
    *(h8v*)(obase + c * 512 + R0 + seg + 8) = h1;
}

// ---------------- proj3: M=4096 N=512 K=512, 128x128 tiles (2 heads/block) -
__global__ __launch_bounds__(256) void proj3_kernel(
    const _Float16* __restrict__ Qh, const _Float16* __restrict__ Kh,
    const _Float16* __restrict__ Vh,
    const _Float16* __restrict__ Wqt, const _Float16* __restrict__ Wkt,
    const _Float16* __restrict__ Wvt,
    _Float16* __restrict__ Qp, _Float16* __restrict__ Kp, _Float16* __restrict__ Vtp)
{
    __shared__ alignas(16) _Float16 As[2][128 * 64];
    __shared__ alignas(16) _Float16 Bs[2][128 * 64];
    const int z = blockIdx.z;
    const _Float16* A  = z == 0 ? Qh : z == 1 ? Kh : Vh;
    const _Float16* Bt = z == 0 ? Wqt : z == 1 ? Wkt : Wvt;
    const int tid = threadIdx.x, lane = tid & 63, wid = tid >> 6;
    const int g = lane >> 4, cl = lane & 15;
    const int brow = blockIdx.x * 128, bc = blockIdx.y;   // bc: 2-head col block
    const int wr = (wid >> 1) << 6, wc = (wid & 1) << 6;
    fx4 acc[4][4] = {};

    #define STG(ks, buf) do {                                                  \
        _Pragma("unroll")                                                      \
        for (int i = 0; i < 4; ++i) {                                          \
            int ch = (i << 8) + tid; int row = ch >> 3, c16 = ch & 7;          \
            gload16(A + (size_t)(brow + row) * 512 + (ks) * 64 +               \
                        ((c16 ^ (row & 7)) << 3),                              \
                    &As[buf][((i << 8) + (wid << 6)) << 3]);                   \
        }                                                                      \
        _Pragma("unroll")                                                      \
        for (int i = 0; i < 4; ++i) {                                          \
            int ch = (i << 8) + tid; int row = ch >> 3, c16 = ch & 7;          \
            gload16(Bt + (size_t)(bc * 128 + row) * 512 + (ks) * 64 +          \
                        ((c16 ^ (row & 7)) << 3),                              \
                    &Bs[buf][((i << 8) + (wid << 6)) << 3]);                   \
        }                                                                      \
    } while (0)

    #define CMP(buf) do {                                                      \
        _Pragma("unroll")                                                      \
        for (int ko = 0; ko < 2; ++ko) {                                       \
            int kb = (ko << 5) + (g << 3);                                     \
            h8v af[4], bfr[4];                                                 \
            _Pragma("unroll")                                                  \
            for (int mf = 0; mf < 4; ++mf) {                                   \
                int row = wr + mf * 16 + cl;                                   \
                af[mf] = *(h8v*)&As[buf][(row << 6) + (kb ^ ((row & 7) << 3))];\
            }                                                                  \
            _Pragma("unroll")                                                  \
            for (int nf = 0; nf < 4; ++nf) {                                   \
                int row = wc + nf * 16 + cl;                                   \
                bfr[nf] = *(h8v*)&Bs[buf][(row << 6) + (kb ^ ((row & 7) << 3))];\
            }                                                                  \
            __builtin_amdgcn_s_setprio(1);                                     \
            _Pragma("unroll")                                                  \
            for (int mf = 0; mf < 4; ++mf)                                     \
                _Pragma("unroll")                                              \
                for (int nf = 0; nf < 4; ++nf)                                 \
                    acc[mf][nf] = __builtin_amdgcn_mfma_f32_16x16x32_f16(      \
                        af[mf], bfr[nf], acc[mf][nf], 0, 0, 0);                \
            __builtin_amdgcn_s_setprio(0);                                     \
        }                                                                      \
    } while (0)

    STG(0, 0);
    for (int kk = 0; kk < 4; ++kk) {
        STG(2 * kk + 1, 1);
        VMCNT(8);
        __builtin_amdgcn_s_barrier();
        CMP(0);
        __builtin_amdgcn_s_barrier();
        if (kk < 3) { STG(2 * kk + 2, 0); VMCNT(8); } else { VMCNT(0); }
        __builtin_amdgcn_s_barrier();
        CMP(1);
        __builtin_amdgcn_s_barrier();
    }
    #undef STG
    #undef CMP

    if (z != 2) {  // Q/K: [BH][2048][64]
        _Float16* Out = z == 0 ? Qp : Kp;
        #pragma unroll
        for (int mf = 0; mf < 4; ++mf)
            #pragma unroll
            for (int nf = 0; nf < 4; ++nf)
                #pragma unroll
                for (int r = 0; r < 4; ++r) {
                    int grow = brow + wr + mf * 16 + (g << 2) + r;
                    int coln = (bc << 7) + wc + (nf << 4) + cl;
                    int head = coln >> 6, col = coln & 63;
                    int b = grow >> 11, n = grow & 2047;
                    Out[((((size_t)(b * 8 + head)) * 2048 + n) << 6) + col] = (_Float16)acc[mf][nf][r];
                }
    } else {       // V^T: [BH][64][2048]
        #pragma unroll
        for (int mf = 0; mf < 4; ++mf)
            #pragma unroll
            for (int nf = 0; nf < 4; ++nf) {
                int grow = brow + wr + mf * 16 + (g << 2);
                int coln = (bc << 7) + wc + (nf << 4) + cl;
                int head = coln >> 6, col = coln & 63;
                int b = grow >> 11, m = grow & 2047;
                h4v pk;
                #pragma unroll
                for (int r = 0; r < 4; ++r) pk[r] = (_Float16)acc[mf][nf][r];
                *(h4v*)&Vtp[((((size_t)(b * 8 + head)) * 64 + col) << 11) + m] = pk;
            }
    }
}

// ---------------- final GEMM: Oa fp16 [4096][512] x Pt -> f32 + bias, 128x128
__global__ __launch_bounds__(256) void final_gemm(
    const _Float16* __restrict__ Av, const _Float16* __restrict__ Bt,
    float* __restrict__ O, const float* __restrict__ bias)
{
    __shared__ alignas(16) _Float16 As[2][128 * 64];
    __shared__ alignas(16) _Float16 Bs[2][128 * 64];
    const int tid = threadIdx.x, lane = tid & 63, wid = tid >> 6;
    const int g = lane >> 4, cl = lane & 15;
    const int brow = blockIdx.x * 128, bc = blockIdx.y;
    const int wr = (wid >> 1) << 6, wc = (wid & 1) << 6;
    fx4 acc[4][4] = {};

    #define STG(ks, buf) do {                                                  \
        _Pragma("unroll")                                                      \
        for (int i = 0; i < 4; ++i) {                                          \
            int ch = (i << 8) + tid; int row = ch >> 3, c16 = ch & 7;          \
            gload16(Av + (size_t)(brow + row) * 512 + (ks) * 64 +              \
                        ((c16 ^ (row & 7)) << 3),                              \
                    &As[buf][((i << 8) + (wid << 6)) << 3]);                   \
        }                                                                      \
        _Pragma("unroll")                                                      \
        for (int i = 0; i < 4; ++i) {                                          \
            int ch = (i << 8) + tid; int row = ch >> 3, c16 = ch & 7;          \
            gload16(Bt + (size_t)(bc * 128 + row) * 512 + (ks) * 64 +          \
                        ((c16 ^ (row & 7)) << 3),                              \
                    &Bs[buf][((i << 8) + (wid << 6)) << 3]);                   \
        }                                                                      \
    } while (0)

    #define CMP(buf) do {                                                      \
        _Pragma("unroll")                                                      \
        for (int ko = 0; ko < 2; ++ko) {                                       \
            int kb = (ko << 5) + (g << 3);                                     \
            h8v af[4], bfr[4];                                                 \
            _Pragma("unroll")                                                  \
            for (int mf = 0; mf < 4; ++mf) {                                   \
                int row = wr + mf * 16 + cl;                                   \
                af[mf] = *(h8v*)&As[buf][(row << 6) + (kb ^ ((row & 7) << 3))];\
            }                                                                  \
            _Pragma("unroll")                                                  \
            for (int nf = 0; nf < 4; ++nf) {                                   \
                int row = wc + nf * 16 + cl;                                   \
                bfr[nf] = *(h8v*)&Bs[buf][(row << 6) + (kb ^ ((row & 7) << 3))];\
            }                                                                  \
            __builtin_amdgcn_s_setprio(1);                                     \
            _Pragma("unroll")                                                  \
            for (int mf = 0; mf < 4; ++mf)                                     \
                _Pragma("unroll")                                              \
                for (int nf = 0; nf < 4; ++nf)                                 \
                    acc[mf][nf] = __builtin_amdgcn_mfma_f32_16x16x32_f16(      \
                        af[mf], bfr[nf], acc[mf][nf], 0, 0, 0);                \
            __builtin_amdgcn_s_setprio(0);                                     \
        }                                                                      \
    } while (0)

    STG(0, 0);
    for (int kk = 0; kk < 4; ++kk) {
        STG(2 * kk + 1, 1);
        VMCNT(8);
        __builtin_amdgcn_s_barrier();
        CMP(0);
        __builtin_amdgcn_s_barrier();
        if (kk < 3) { STG(2 * kk + 2, 0); VMCNT(8); } else { VMCNT(0); }
        __builtin_amdgcn_s_barrier();
        CMP(1);
        __builtin_amdgcn_s_barrier();
    }
    #undef STG
    #undef CMP

    #pragma unroll
    for (int mf = 0; mf < 4; ++mf)
        #pragma unroll
        for (int nf = 0; nf < 4; ++nf)
            #pragma unroll
            for (int r = 0; r < 4; ++r) {
                int grow = brow + wr + mf * 16 + (g << 2) + r;
                int col = (bc << 7) + wc + (nf << 4) + cl;
                O[((size_t)grow << 9) + col] = acc[mf][nf][r] + bias[col];
            }
}

// ---------------- flash attention: 2 waves/block, 32 q-rows/wave -----------
// Qp/Kp: [BH][2048][64] fp16 (Q pre-scaled by log2e/8). Vg: [BH][64][2048].
// Oa: [B][2048][H][64] fp16.  Q-tile 64/block, grid 512 (2 blocks/CU).
// St = mfma(Kfrag, Q_as_B), C-init=-12, exp2 domain: lane holds
// P[q=mf*16+cl][kv=16nf+4g+r].  cvt_pkrtz -> ds_write_b32 into stride-144
// P buffer -> ds_read_b128 A-frags.  Row-sum via ones-B MFMA (no shuffles).
// LDS: Kd 2x8192 | Vd 2x8192 | P 2 waves x 4608 = 41984 B total.
__global__ __launch_bounds__(128) void attn_kernel(
    const _Float16* __restrict__ Qp, const _Float16* __restrict__ Kp,
    const _Float16* __restrict__ Vg, _Float16* __restrict__ Oa)
{
    __shared__ alignas(16) char smem[41984];
    _Float16* KdU = (_Float16*)smem;     // fp16 units: Kd buf*4096, Vd +8192
    char* smemc = smem;
    const int tid = threadIdx.x, lane = tid & 63, wid = tid >> 6;
    const int g = lane >> 4, cl = lane & 15;
    int lin = blockIdx.y * 32 + blockIdx.x;   // 0..511
    int xcd = lin & 7, slot = lin >> 3;       // each XCD owns 2 heads (1MB KV, L2-fit)
    int bh = xcd * 2 + (slot & 1);
    int qbase = (slot >> 1) << 6;
    const size_t hbase = (size_t)bh * (2048 * 64);

    // K/V fragment LDS offsets (fp16 units)
    int kf_off[2][4];
    #pragma unroll
    for (int ko = 0; ko < 2; ++ko)
        #pragma unroll
        for (int nf = 0; nf < 4; ++nf) {
            int row = (nf << 4) + cl;
            kf_off[ko][nf] = (row << 6) + (((ko << 5) + (g << 3)) ^ ((row & 7) << 3));
        }
    // P buffer: per wave 32 rows x 144B @32768
    const int ps_w = 32768 + wid * 4608 + cl * 144 + (g << 3);   // + mf*2304 + 32nf + 4h
    const int ps_r = 32768 + wid * 4608 + cl * 144 + (g << 4);   // + mf*2304 + 64kk

    // ---- stage Q (64x64) into Kd buf0, read Q as B-fragments
    #pragma unroll
    for (int j = 0; j < 4; ++j) {
        int ch = (j << 7) + tid; int row = ch >> 3, c16 = ch & 7;
        gload16(Qp + hbase + ((size_t)(qbase + row) << 6) + ((c16 ^ (row & 7)) << 3),
                &KdU[((j << 7) + (wid << 6)) << 3]);
    }
    VMCNT(0);
    __builtin_amdgcn_s_barrier();
    h8v qf[2][2];
    #pragma unroll
    for (int mf = 0; mf < 2; ++mf)
        #pragma unroll
        for (int ko = 0; ko < 2; ++ko) {
            int row = (wid << 5) + (mf << 4) + cl;
            qf[mf][ko] = *(h8v*)&KdU[(row << 6) + ((((ko << 5) + (g << 3))) ^ ((row & 7) << 3))];
        }
    LGKMCNT0;
    __builtin_amdgcn_s_barrier();   // all waves read Q before K overwrites

    h8v ones;
    #pragma unroll
    for (int j = 0; j < 8; ++j) ones[j] = (_Float16)1.0f;
    fx4 oacc[2][4] = {};
    fx4 lacc[2] = {};

    #define STAGE_KV(t, buf) do {                                              \
        _Pragma("unroll")                                                      \
        for (int j = 0; j < 4; ++j) {                                          \
            int ch = (j << 7) + tid; int row = ch >> 3, c16 = ch & 7;          \
            int sw = (c16 ^ (row & 7)) << 3;                                   \
            int du = (((j << 7) + (wid << 6)) << 3) + (buf) * 4096;            \
            gload16(Kp + hbase + ((size_t)(((t) << 6) + row) << 6) + sw,       \
                    &KdU[du]);                                                 \
            gload16(Vg + hbase + ((size_t)row << 11) + ((t) << 6) + sw,        \
                    &KdU[du + 8192]);                                          \
        }                                                                      \
    } while (0)

    #define CMP(buf) do {                                                      \
        const int bofs = (buf) * 4096;                                         \
        h8v kf[2][4];                                                          \
        _Pragma("unroll")                                                      \
        for (int ko = 0; ko < 2; ++ko)                                         \
            _Pragma("unroll")                                                  \
            for (int nf = 0; nf < 4; ++nf)                                     \
                kf[ko][nf] = *(h8v*)&KdU[bofs + kf_off[ko][nf]];               \
        fx4 st[2][4];                                                          \
        _Pragma("unroll")                                                      \
        for (int mf = 0; mf < 2; ++mf)                                         \
            _Pragma("unroll")                                                  \
            for (int nf = 0; nf < 4; ++nf)                                     \
                st[mf][nf] = (fx4){-12.f, -12.f, -12.f, -12.f};                \
        __builtin_amdgcn_s_setprio(1);                                         \
        _Pragma("unroll")                                                      \
        for (int ko = 0; ko < 2; ++ko)                                         \
            _Pragma("unroll")                                                  \
            for (int mf = 0; mf < 2; ++mf)                                     \
                _Pragma("unroll")                                              \
                for (int nf = 0; nf < 4; ++nf)                                 \
                    st[mf][nf] = __builtin_amdgcn_mfma_f32_16x16x32_f16(       \
                        kf[ko][nf], qf[mf][ko], st[mf][nf], 0, 0, 0);          \
        __builtin_amdgcn_s_setprio(0);                                         \
        _Pragma("unroll")                                                      \
        for (int mf = 0; mf < 2; ++mf)                                         \
            _Pragma("unroll")                                                  \
            for (int nf = 0; nf < 4; ++nf)                                     \
                _Pragma("unroll")                                              \
                for (int h = 0; h < 2; ++h) {                                  \
                    float p0 = __builtin_amdgcn_exp2f(st[mf][nf][2 * h]);      \
                    float p1 = __builtin_amdgcn_exp2f(st[mf][nf][2 * h + 1]);  \
                    fp16x2 pk = __builtin_amdgcn_cvt_pkrtz(p0, p1);            \
                    *(fp16x2*)(smemc + ps_w + mf * 2304 + 32 * nf + 4 * h) = pk;\
                }                                                              \
        h8v pa[2][2], vf[2][4];                                                \
        _Pragma("unroll")                                                      \
        for (int kk = 0; kk < 2; ++kk) {                                       \
            _Pragma("unroll")                                                  \
            for (int mf = 0; mf < 2; ++mf)                                     \
                pa[mf][kk] = *(h8v*)(smemc + ps_r + mf * 2304 + 64 * kk);      \
            _Pragma("unroll")                                                  \
            for (int of = 0; of < 4; ++of)                                     \
                vf[kk][of] = *(h8v*)&KdU[bofs + 8192 + kf_off[kk][of]];        \
        }                                                                      \
        __builtin_amdgcn_s_setprio(1);                                         \
        _Pragma("unroll")                                                      \
        for (int kk = 0; kk < 2; ++kk)                                         \
            _Pragma("unroll")                                                  \
            for (int mf = 0; mf < 2; ++mf) {                                   \
                _Pragma("unroll")                                              \
                for (int of = 0; of < 4; ++of)                                 \
                    oacc[mf][of] = __builtin_amdgcn_mfma_f32_16x16x32_f16(     \
                        pa[mf][kk], vf[kk][of], oacc[mf][of], 0, 0, 0);        \
                lacc[mf] = __builtin_amdgcn_mfma_f32_16x16x32_f16(             \
                    pa[mf][kk], ones, lacc[mf], 0, 0, 0);                      \
            }                                                                  \
        __builtin_amdgcn_s_setprio(0);                                         \
    } while (0)

    STAGE_KV(0, 0);
    for (int tt = 0; tt < 16; ++tt) {
        STAGE_KV(2 * tt + 1, 1);
        VMCNT(8);
        __builtin_amdgcn_s_barrier();
        CMP(0);
        __builtin_amdgcn_s_barrier();
        if (tt < 15) { STAGE_KV(2 * tt + 2, 0); VMCNT(8); } else { VMCNT(0); }
        __builtin_amdgcn_s_barrier();
        CMP(1);
        __builtin_amdgcn_s_barrier();
    }
    #undef STAGE_KV
    #undef CMP

    // epilogue: q = qbase + wid*32 + mf*16 + 4g + r; o = of*16 + cl
    int b = bh >> 3, h = bh & 7;
    #pragma unroll
    for (int mf = 0; mf < 2; ++mf)
        #pragma unroll
        for (int r = 0; r < 4; ++r) {
            float inv = 1.0f / lacc[mf][r];
            int n = qbase + (wid << 5) + (mf << 4) + (g << 2) + r;
            size_t base = ((((size_t)b * 2048 + n) * 8) + h) << 6;
            #pragma unroll
            for (int of = 0; of < 4; ++of)
                Oa[base + (of << 4) + cl] = (_Float16)(oacc[mf][of][r] * inv);
        }
}

extern "C" void kernel_launch(void* const* d_in, const int* in_sizes, int n_in,
                              void* d_out, int out_size, void* d_ws, size_t ws_size,
                              hipStream_t stream) {
    const float* query = (const float*)d_in[0];
    const float* key   = (const float*)d_in[1];
    const float* value = (const float*)d_in[2];
    const float* wq    = (const float*)d_in[3];
    const float* wk    = (const float*)d_in[4];
    const float* wv    = (const float*)d_in[5];
    const float* wp    = (const float*)d_in[6];
    const float* bias  = (const float*)d_in[7];
    float* out = (float*)d_out;

    char* ws = (char*)d_ws;
    const size_t MB = 1 << 20;
    _Float16* Wqt = (_Float16*)(ws);
    _Float16* Wkt = (_Float16*)(ws + MB / 2);
    _Float16* Wvt = (_Float16*)(ws + 2 * (MB / 2));
    _Float16* Pt  = (_Float16*)(ws + 3 * (MB / 2));
    _Float16* Qh  = (_Float16*)(ws + 2 * MB);          // 4MB; Oa reuses this
    _Float16* Kh  = (_Float16*)(ws + 6 * MB);
    _Float16* Vh  = (_Float16*)(ws + 10 * MB);
    _Float16* Qp  = (_Float16*)(ws + 14 * MB);
    _Float16* Kp  = (_Float16*)(ws + 18 * MB);
    _Float16* Vt  = (_Float16*)(ws + 22 * MB);
    _Float16* Oa  = Qh;

    prep_kernel<<<dim3(1024, 7), 256, 0, stream>>>(query, key, value, wq, wk, wv, wp,
                                                   Qh, Kh, Vh, Wqt, Wkt, Wvt, Pt);
    proj3_kernel<<<dim3(32, 4, 3), 256, 0, stream>>>(Qh, Kh, Vh, Wqt, Wkt, Wvt, Qp, Kp, Vt);
    attn_kernel<<<dim3(32, 16), 128, 0, stream>>>(Qp, Kp, Vt, Oa);
    final_gemm<<<dim3(32, 4), 256, 0, stream>>>(Oa, Pt, out, bias);
}

// Round 6
// 135.524 us; speedup vs baseline: 1.0883x; 1.0883x over previous
//
#include <hip/hip_runtime.h>

// MultiHeadAttention: B=2, T=S=2048, D=512, H=8, HS=64
// prep -> proj3 (128x64-col MFMA GEMMs, 3 blk/CU) -> attn (flash, 4 waves =
//   2 q-halves x 2 kv-halves, swapped-QK, static-max exp2(s-12), ones-MFMA
//   rowsum, conflict-free stride-72 P buffer, end-of-kernel wave merge)
//   -> final GEMM (+bias, f32 out).
// ws (26MB): Wqt|Wkt|Wvt|Pt (512KB ea) | Qh|Kh|Vh (4MB ea; Oa reuses Qh) | Qp|Kp|Vt

typedef float    fx4 __attribute__((ext_vector_type(4)));
typedef _Float16 h8v __attribute__((ext_vector_type(8)));
typedef __fp16   fp16x2 __attribute__((ext_vector_type(2)));
typedef _Float16 h4v __attribute__((ext_vector_type(4)));

#define LOG2E 1.4426950408889634f

typedef const __attribute__((address_space(1))) void* gptr_t;
typedef __attribute__((address_space(3))) void* lptr_t;
__device__ __forceinline__ void gload16(const void* g, void* l) {
    __builtin_amdgcn_global_load_lds((gptr_t)g, (lptr_t)l, 16, 0, 0);
}
#define VMCNT(n) asm volatile("s_waitcnt vmcnt(" #n ")" ::: "memory")
#define LGKMCNT0 asm volatile("s_waitcnt lgkmcnt(0)" ::: "memory")

// ---------------- prep: y=0..2 convert q/k/v to fp16; y=3..6 transpose weights
__global__ __launch_bounds__(256) void prep_kernel(
    const float* __restrict__ q, const float* __restrict__ k, const float* __restrict__ v,
    const float* __restrict__ wq, const float* __restrict__ wk,
    const float* __restrict__ wv, const float* __restrict__ wp,
    _Float16* __restrict__ Qh, _Float16* __restrict__ Kh, _Float16* __restrict__ Vh,
    _Float16* __restrict__ Wqt, _Float16* __restrict__ Wkt,
    _Float16* __restrict__ Wvt, _Float16* __restrict__ Pt)
{
    __shared__ float tile[64 * 65];
    int y = blockIdx.y;
    if (y < 3) {
        const float* src = y == 0 ? q : y == 1 ? k : v;
        _Float16* dst = y == 0 ? Qh : y == 1 ? Kh : Vh;
        int i = (blockIdx.x * 256 + threadIdx.x) * 8;
        float4 f0 = *(const float4*)(src + i);
        float4 f1 = *(const float4*)(src + i + 4);
        h8v hv;
        hv[0] = (_Float16)f0.x; hv[1] = (_Float16)f0.y;
        hv[2] = (_Float16)f0.z; hv[3] = (_Float16)f0.w;
        hv[4] = (_Float16)f1.x; hv[5] = (_Float16)f1.y;
        hv[6] = (_Float16)f1.z; hv[7] = (_Float16)f1.w;
        *(h8v*)(dst + i) = hv;
        return;
    }
    if (blockIdx.x >= 64) return;
    int w = y - 3;
    const float* in = w == 0 ? wq : w == 1 ? wk : w == 2 ? wv : wp;
    _Float16* out = w == 0 ? Wqt : w == 1 ? Wkt : w == 2 ? Wvt : Pt;
    float scale = (w == 0) ? 0.125f * LOG2E : 1.0f;
    const float* src; _Float16* obase; int R0, SI;
    if (w < 3) {                       // [8h][512][64] -> [8h][64][512]
        int h = blockIdx.x >> 3, kt = blockIdx.x & 7;
        src = in + h * 32768 + (kt * 64) * 64; SI = 64;
        obase = out + h * 32768; R0 = kt * 64;
    } else {                           // [512][512] -> [512][512]^T
        int rt = blockIdx.x >> 3, ct = blockIdx.x & 7;
        src = in + (rt * 64) * 512 + ct * 64; SI = 512;
        obase = out + (ct * 64) * 512; R0 = rt * 64;
    }
    int t = threadIdx.x;
    int r = t >> 4, c4 = (t & 15) << 2;
    #pragma unroll
    for (int p = 0; p < 4; ++p) {
        float4 f = *(const float4*)(src + (r + p * 16) * SI + c4);
        tile[(c4 + 0) * 65 + r + p * 16] = f.x;
        tile[(c4 + 1) * 65 + r + p * 16] = f.y;
        tile[(c4 + 2) * 65 + r + p * 16] = f.z;
        tile[(c4 + 3) * 65 + r + p * 16] = f.w;
    }
    __syncthreads();
    int c = t >> 2, seg = (t & 3) << 4;
    h8v h0, h1;
    #pragma unroll
    for (int j = 0; j < 8; ++j) {
        h0[j] = (_Float16)(tile[c * 65 + seg + j] * scale);
        h1[j] = (_Float16)(tile[c * 65 + seg + 8 + j] * scale);
    }
    *(h8v*)(obase + c * 512 + R0 + seg) = h0;
    *(h8v*)(obase + c * 512 + R0 + seg + 8) = h1;
}

// ---------------- proj3: M=4096 N=512(8hx64) K=512, 128x64 tiles, 3 blk/CU -
__global__ __launch_bounds__(256) void proj3_kernel(
    const _Float16* __restrict__ Qh, const _Float16* __restrict__ Kh,
    const _Float16* __restrict__ Vh,
    const _Float16* __restrict__ Wqt, const _Float16* __restrict__ Wkt,
    const _Float16* __restrict__ Wvt,
    _Float16* __restrict__ Qp, _Float16* __restrict__ Kp, _Float16* __restrict__ Vtp)
{
    __shared__ alignas(16) _Float16 As[2][128 * 64];
    __shared__ alignas(16) _Float16 Bs[2][64 * 64];
    const int z = blockIdx.z;
    const _Float16* A  = z == 0 ? Qh : z == 1 ? Kh : Vh;
    const _Float16* Bt = z == 0 ? Wqt : z == 1 ? Wkt : Wvt;
    const int tid = threadIdx.x, lane = tid & 63, wid = tid >> 6;
    const int g = lane >> 4, cl = lane & 15;
    const int brow = blockIdx.x * 128, bc = blockIdx.y;
    const int wr = (wid >> 1) * 64, wc = (wid & 1) * 32;
    fx4 acc[4][2] = {};

    #define STG(ks, buf) do {                                                  \
        _Pragma("unroll")                                                      \
        for (int i = 0; i < 4; ++i) {                                          \
            int ch = (i << 8) + tid; int row = ch >> 3, c16 = ch & 7;          \
            gload16(A + (size_t)(brow + row) * 512 + (ks) * 64 +               \
                        ((c16 ^ (row & 7)) << 3),                              \
                    &As[buf][((i << 8) + (wid << 6)) << 3]);                   \
        }                                                                      \
        _Pragma("unroll")                                                      \
        for (int i = 0; i < 2; ++i) {                                          \
            int ch = (i << 8) + tid; int row = ch >> 3, c16 = ch & 7;          \
            gload16(Bt + (size_t)(bc * 64 + row) * 512 + (ks) * 64 +           \
                        ((c16 ^ (row & 7)) << 3),                              \
                    &Bs[buf][((i << 8) + (wid << 6)) << 3]);                   \
        }                                                                      \
    } while (0)

    #define CMP(buf) do {                                                      \
        _Pragma("unroll")                                                      \
        for (int ko = 0; ko < 2; ++ko) {                                       \
            int kb = (ko << 5) + (g << 3);                                     \
            h8v af[4], bfr[2];                                                 \
            _Pragma("unroll")                                                  \
            for (int mf = 0; mf < 4; ++mf) {                                   \
                int row = wr + mf * 16 + cl;                                   \
                af[mf] = *(h8v*)&As[buf][(row << 6) + (kb ^ ((row & 7) << 3))];\
            }                                                                  \
            _Pragma("unroll")                                                  \
            for (int nf = 0; nf < 2; ++nf) {                                   \
                int row = wc + nf * 16 + cl;                                   \
                bfr[nf] = *(h8v*)&Bs[buf][(row << 6) + (kb ^ ((row & 7) << 3))];\
            }                                                                  \
            __builtin_amdgcn_s_setprio(1);                                     \
            _Pragma("unroll")                                                  \
            for (int mf = 0; mf < 4; ++mf)                                     \
                _Pragma("unroll")                                              \
                for (int nf = 0; nf < 2; ++nf)                                 \
                    acc[mf][nf] = __builtin_amdgcn_mfma_f32_16x16x32_f16(      \
                        af[mf], bfr[nf], acc[mf][nf], 0, 0, 0);                \
            __builtin_amdgcn_s_setprio(0);                                     \
        }                                                                      \
    } while (0)

    STG(0, 0);
    for (int kk = 0; kk < 4; ++kk) {
        STG(2 * kk + 1, 1);
        VMCNT(6);
        __builtin_amdgcn_s_barrier();
        CMP(0);
        __builtin_amdgcn_s_barrier();
        if (kk < 3) { STG(2 * kk + 2, 0); VMCNT(6); } else { VMCNT(0); }
        __builtin_amdgcn_s_barrier();
        CMP(1);
        __builtin_amdgcn_s_barrier();
    }
    #undef STG
    #undef CMP

    if (z != 2) {  // Q/K: [BH][2048][64]
        _Float16* Out = z == 0 ? Qp : Kp;
        #pragma unroll
        for (int mf = 0; mf < 4; ++mf)
            #pragma unroll
            for (int nf = 0; nf < 2; ++nf)
                #pragma unroll
                for (int r = 0; r < 4; ++r) {
                    int grow = brow + wr + mf * 16 + (g << 2) + r;
                    int col = wc + nf * 16 + cl;
                    int b = grow >> 11, n = grow & 2047;
                    Out[((((size_t)(b * 8 + bc)) * 2048 + n) << 6) + col] = (_Float16)acc[mf][nf][r];
                }
    } else {       // V^T: [BH][64][2048]
        #pragma unroll
        for (int mf = 0; mf < 4; ++mf)
            #pragma unroll
            for (int nf = 0; nf < 2; ++nf) {
                int grow = brow + wr + mf * 16 + (g << 2);
                int col = wc + nf * 16 + cl;
                int b = grow >> 11, m = grow & 2047;
                h4v pk;
                #pragma unroll
                for (int r = 0; r < 4; ++r) pk[r] = (_Float16)acc[mf][nf][r];
                *(h4v*)&Vtp[((((size_t)(b * 8 + bc)) * 64 + col) << 11) + m] = pk;
            }
    }
}

// ---------------- final GEMM: Oa fp16 [4096][512] x Pt -> f32 + bias -------
__global__ __launch_bounds__(256) void final_gemm(
    const _Float16* __restrict__ Av, const _Float16* __restrict__ Bt,
    float* __restrict__ O, const float* __restrict__ bias)
{
    __shared__ alignas(16) _Float16 As[2][128 * 64];
    __shared__ alignas(16) _Float16 Bs[2][64 * 64];
    const int tid = threadIdx.x, lane = tid & 63, wid = tid >> 6;
    const int g = lane >> 4, cl = lane & 15;
    const int brow = blockIdx.x * 128, bc = blockIdx.y;
    const int wr = (wid >> 1) * 64, wc = (wid & 1) * 32;
    fx4 acc[4][2] = {};

    #define STG(ks, buf) do {                                                  \
        _Pragma("unroll")                                                      \
        for (int i = 0; i < 4; ++i) {                                          \
            int ch = (i << 8) + tid; int row = ch >> 3, c16 = ch & 7;          \
            gload16(Av + (size_t)(brow + row) * 512 + (ks) * 64 +              \
                        ((c16 ^ (row & 7)) << 3),                              \
                    &As[buf][((i << 8) + (wid << 6)) << 3]);                   \
        }                                                                      \
        _Pragma("unroll")                                                      \
        for (int i = 0; i < 2; ++i) {                                          \
            int ch = (i << 8) + tid; int row = ch >> 3, c16 = ch & 7;          \
            gload16(Bt + (size_t)(bc * 64 + row) * 512 + (ks) * 64 +           \
                        ((c16 ^ (row & 7)) << 3),                              \
                    &Bs[buf][((i << 8) + (wid << 6)) << 3]);                   \
        }                                                                      \
    } while (0)

    #define CMP(buf) do {                                                      \
        _Pragma("unroll")                                                      \
        for (int ko = 0; ko < 2; ++ko) {                                       \
            int kb = (ko << 5) + (g << 3);                                     \
            h8v af[4], bfr[2];                                                 \
            _Pragma("unroll")                                                  \
            for (int mf = 0; mf < 4; ++mf) {                                   \
                int row = wr + mf * 16 + cl;                                   \
                af[mf] = *(h8v*)&As[buf][(row << 6) + (kb ^ ((row & 7) << 3))];\
            }                                                                  \
            _Pragma("unroll")                                                  \
            for (int nf = 0; nf < 2; ++nf) {                                   \
                int row = wc + nf * 16 + cl;                                   \
                bfr[nf] = *(h8v*)&Bs[buf][(row << 6) + (kb ^ ((row & 7) << 3))];\
            }                                                                  \
            __builtin_amdgcn_s_setprio(1);                                     \
            _Pragma("unroll")                                                  \
            for (int mf = 0; mf < 4; ++mf)                                     \
                _Pragma("unroll")                                              \
                for (int nf = 0; nf < 2; ++nf)                                 \
                    acc[mf][nf] = __builtin_amdgcn_mfma_f32_16x16x32_f16(      \
                        af[mf], bfr[nf], acc[mf][nf], 0, 0, 0);                \
            __builtin_amdgcn_s_setprio(0);                                     \
        }                                                                      \
    } while (0)

    STG(0, 0);
    for (int kk = 0; kk < 4; ++kk) {
        STG(2 * kk + 1, 1);
        VMCNT(6);
        __builtin_amdgcn_s_barrier();
        CMP(0);
        __builtin_amdgcn_s_barrier();
        if (kk < 3) { STG(2 * kk + 2, 0); VMCNT(6); } else { VMCNT(0); }
        __builtin_amdgcn_s_barrier();
        CMP(1);
        __builtin_amdgcn_s_barrier();
    }
    #undef STG
    #undef CMP

    #pragma unroll
    for (int mf = 0; mf < 4; ++mf)
        #pragma unroll
        for (int nf = 0; nf < 2; ++nf)
            #pragma unroll
            for (int r = 0; r < 4; ++r) {
                int grow = brow + wr + mf * 16 + (g << 2) + r;
                int col = (bc << 6) + wc + nf * 16 + cl;
                O[((size_t)grow << 9) + col] = acc[mf][nf][r] + bias[col];
            }
}

// ---------------- flash attention: 4 waves = 2 q-halves x 2 kv-halves ------
// Qp/Kp: [BH][2048][64] fp16 (Q pre-scaled by log2e/8). Vg: [BH][64][2048].
// Oa: [B][2048][H][64] fp16.  Q-tile 64/block, grid 512 (2 blk/CU, 2 w/SIMD).
// Wave w: q rows (w&1)*32.., kv rows (w>>1)*32.. of each staged 64-kv tile.
// St = mfma(Kfrag, Q_as_B), C-init=-12, exp2 domain. P buffer: stride-72 rows,
// b64 writes / 2xb64 reads -> zero bank conflicts. Rowsum via ones-B MFMA.
// Static-max => cross-wave (kv halves) merge is pure add at the end via LDS.
// LDS: Kd 2x8KB | Vd 2x8KB | P 4 waves x 2304B = 41984 B.
__global__ __launch_bounds__(256) void attn_kernel(
    const _Float16* __restrict__ Qp, const _Float16* __restrict__ Kp,
    const _Float16* __restrict__ Vg, _Float16* __restrict__ Oa)
{
    __shared__ alignas(16) char smem[41984];
    _Float16* KdU = (_Float16*)smem;     // fp16 units: Kd buf*4096, Vd 8192+buf*4096
    char* smemc = smem;
    const int tid = threadIdx.x, lane = tid & 63, wid = tid >> 6;
    const int g = lane >> 4, cl = lane & 15;
    const int qh = wid & 1, kvh = wid >> 1;
    int lin = blockIdx.x;                // 0..511
    int xcd = lin & 7, slot = lin >> 3;  // each XCD owns 2 heads (1MB KV, L2-fit)
    int bh = xcd * 2 + (slot & 1);
    int qbase = (slot >> 1) << 6;        // 32 q-tiles of 64
    const size_t hbase = (size_t)bh * (2048 * 64);

    // K-frag offsets: row = kvh*32 + nf*16 + cl, d-chunk ko*32 + g*8
    int kf_off[2][2];
    #pragma unroll
    for (int ko = 0; ko < 2; ++ko)
        #pragma unroll
        for (int nf = 0; nf < 2; ++nf) {
            int row = (kvh << 5) + (nf << 4) + cl;
            kf_off[ko][nf] = (row << 6) + (((ko << 5) + (g << 3)) ^ ((row & 7) << 3));
        }
    // V-frag offsets: row = of*16 + cl, kv-chunk kvh*32 + g*8
    int vf_off[4];
    #pragma unroll
    for (int of = 0; of < 4; ++of) {
        int row = (of << 4) + cl;
        vf_off[of] = (row << 6) + (((kvh << 5) + (g << 3)) ^ ((row & 7) << 3));
    }
    // P buffer: per-wave 32 rows x 72B @32768 (word starts 2(9cl+g): conflict-free)
    const int pw = 32768 + wid * 2304 + cl * 72;

    // ---- stage Q (64x64) into Kd buf0, read Q as B-fragments
    #pragma unroll
    for (int j = 0; j < 2; ++j) {
        int ch = (j << 8) + tid; int row = ch >> 3, c16 = ch & 7;
        gload16(Qp + hbase + ((size_t)(qbase + row) << 6) + ((c16 ^ (row & 7)) << 3),
                &KdU[((j << 8) + (wid << 6)) << 3]);
    }
    VMCNT(0);
    __builtin_amdgcn_s_barrier();
    h8v qf[2][2];
    #pragma unroll
    for (int mf = 0; mf < 2; ++mf)
        #pragma unroll
        for (int ko = 0; ko < 2; ++ko) {
            int row = (qh << 5) + (mf << 4) + cl;
            qf[mf][ko] = *(h8v*)&KdU[(row << 6) + ((((ko << 5) + (g << 3))) ^ ((row & 7) << 3))];
        }
    LGKMCNT0;
    __builtin_amdgcn_s_barrier();   // all waves read Q before K overwrites

    h8v ones;
    #pragma unroll
    for (int j = 0; j < 8; ++j) ones[j] = (_Float16)1.0f;
    fx4 oacc[2][4] = {};
    fx4 lacc[2] = {};

    #define STAGE_KV(t, buf) do {                                              \
        _Pragma("unroll")                                                      \
        for (int j = 0; j < 2; ++j) {                                          \
            int ch = (j << 8) + tid; int row = ch >> 3, c16 = ch & 7;          \
            int sw = (c16 ^ (row & 7)) << 3;                                   \
            int du = (((j << 8) + (wid << 6)) << 3) + (buf) * 4096;            \
            gload16(Kp + hbase + ((size_t)(((t) << 6) + row) << 6) + sw,       \
                    &KdU[du]);                                                 \
            gload16(Vg + hbase + ((size_t)row << 11) + ((t) << 6) + sw,        \
                    &KdU[du + 8192]);                                          \
        }                                                                      \
    } while (0)

    #define CMP(buf) do {                                                      \
        const int bofs = (buf) * 4096;                                         \
        h8v kf[2][2];                                                          \
        _Pragma("unroll")                                                      \
        for (int ko = 0; ko < 2; ++ko)                                         \
            _Pragma("unroll")                                                  \
            for (int nf = 0; nf < 2; ++nf)                                     \
                kf[ko][nf] = *(h8v*)&KdU[bofs + kf_off[ko][nf]];               \
        fx4 st[2][2];                                                          \
        _Pragma("unroll")                                                      \
        for (int mf = 0; mf < 2; ++mf)                                         \
            _Pragma("unroll")                                                  \
            for (int nf = 0; nf < 2; ++nf)                                     \
                st[mf][nf] = (fx4){-12.f, -12.f, -12.f, -12.f};                \
        __builtin_amdgcn_s_setprio(1);                                         \
        _Pragma("unroll")                                                      \
        for (int ko = 0; ko < 2; ++ko)                                         \
            _Pragma("unroll")                                                  \
            for (int mf = 0; mf < 2; ++mf)                                     \
                _Pragma("unroll")                                              \
                for (int nf = 0; nf < 2; ++nf)                                 \
                    st[mf][nf] = __builtin_amdgcn_mfma_f32_16x16x32_f16(       \
                        kf[ko][nf], qf[mf][ko], st[mf][nf], 0, 0, 0);          \
        __builtin_amdgcn_s_setprio(0);                                         \
        _Pragma("unroll")                                                      \
        for (int mf = 0; mf < 2; ++mf)                                         \
            _Pragma("unroll")                                                  \
            for (int nf = 0; nf < 2; ++nf) {                                   \
                float p0 = __builtin_amdgcn_exp2f(st[mf][nf][0]);              \
                float p1 = __builtin_amdgcn_exp2f(st[mf][nf][1]);              \
                float p2 = __builtin_amdgcn_exp2f(st[mf][nf][2]);              \
                float p3 = __builtin_amdgcn_exp2f(st[mf][nf][3]);              \
                fp16x2 a0 = __builtin_amdgcn_cvt_pkrtz(p0, p1);                \
                fp16x2 a1 = __builtin_amdgcn_cvt_pkrtz(p2, p3);                \
                h4v wv_;                                                       \
                wv_[0] = (_Float16)a0[0]; wv_[1] = (_Float16)a0[1];            \
                wv_[2] = (_Float16)a1[0]; wv_[3] = (_Float16)a1[1];            \
                *(h4v*)(smemc + pw + mf * 1152 + nf * 32 + (g << 3)) = wv_;    \
            }                                                                  \
        h8v pa[2], vf[4];                                                      \
        _Pragma("unroll")                                                      \
        for (int mf = 0; mf < 2; ++mf) {                                       \
            h4v lo = *(h4v*)(smemc + pw + mf * 1152 + (g << 4));               \
            h4v hi = *(h4v*)(smemc + pw + mf * 1152 + (g << 4) + 8);           \
            pa[mf][0] = lo[0]; pa[mf][1] = lo[1];                              \
            pa[mf][2] = lo[2]; pa[mf][3] = lo[3];                              \
            pa[mf][4] = hi[0]; pa[mf][5] = hi[1];                              \
            pa[mf][6] = hi[2]; pa[mf][7] = hi[3];                              \
        }                                                                      \
        _Pragma("unroll")                                                      \
        for (int of = 0; of < 4; ++of)                                         \
            vf[of] = *(h8v*)&KdU[bofs + 8192 + vf_off[of]];                    \
        __builtin_amdgcn_s_setprio(1);                                         \
        _Pragma("unroll")                                                      \
        for (int mf = 0; mf < 2; ++mf) {                                       \
            _Pragma("unroll")                                                  \
            for (int of = 0; of < 4; ++of)                                     \
                oacc[mf][of] = __builtin_amdgcn_mfma_f32_16x16x32_f16(         \
                    pa[mf], vf[of], oacc[mf][of], 0, 0, 0);                    \
            lacc[mf] = __builtin_amdgcn_mfma_f32_16x16x32_f16(                 \
                pa[mf], ones, lacc[mf], 0, 0, 0);                              \
        }                                                                      \
        __builtin_amdgcn_s_setprio(0);                                         \
    } while (0)

    STAGE_KV(0, 0);
    for (int tt = 0; tt < 16; ++tt) {
        STAGE_KV(2 * tt + 1, 1);
        VMCNT(4);
        __builtin_amdgcn_s_barrier();
        CMP(0);
        __builtin_amdgcn_s_barrier();
        if (tt < 15) { STAGE_KV(2 * tt + 2, 0); VMCNT(4); } else { VMCNT(0); }
        __builtin_amdgcn_s_barrier();
        CMP(1);
        __builtin_amdgcn_s_barrier();
    }
    #undef STAGE_KV
    #undef CMP

    // ---- cross-wave merge (kv halves) + normalize + store
    int moff = qh * 10240 + lane * 160;
    if (kvh == 1) {
        #pragma unroll
        for (int mf = 0; mf < 2; ++mf)
            #pragma unroll
            for (int of = 0; of < 4; ++of)
                *(fx4*)(smemc + moff + ((mf << 2) + of) * 16) = oacc[mf][of];
        *(fx4*)(smemc + moff + 128) = lacc[0];
        *(fx4*)(smemc + moff + 144) = lacc[1];
    }
    __syncthreads();
    if (kvh == 0) {
        #pragma unroll
        for (int mf = 0; mf < 2; ++mf)
            #pragma unroll
            for (int of = 0; of < 4; ++of)
                oacc[mf][of] += *(fx4*)(smemc + moff + ((mf << 2) + of) * 16);
        lacc[0] += *(fx4*)(smemc + moff + 128);
        lacc[1] += *(fx4*)(smemc + moff + 144);
        int b = bh >> 3, h = bh & 7;
        #pragma unroll
        for (int mf = 0; mf < 2; ++mf)
            #pragma unroll
            for (int r = 0; r < 4; ++r) {
                float inv = 1.0f / lacc[mf][r];
                int n = qbase + (qh << 5) + (mf << 4) + (g << 2) + r;
                size_t base = ((((size_t)b * 2048 + n) * 8) + h) << 6;
                #pragma unroll
                for (int of = 0; of < 4; ++of)
                    Oa[base + (of << 4) + cl] = (_Float16)(oacc[mf][of][r] * inv);
            }
    }
}

extern "C" void kernel_launch(void* const* d_in, const int* in_sizes, int n_in,
                              void* d_out, int out_size, void* d_ws, size_t ws_size,
                              hipStream_t stream) {
    const float* query = (const float*)d_in[0];
    const float* key   = (const float*)d_in[1];
    const float* value = (const float*)d_in[2];
    const float* wq    = (const float*)d_in[3];
    const float* wk    = (const float*)d_in[4];
    const float* wv    = (const float*)d_in[5];
    const float* wp    = (const float*)d_in[6];
    const float* bias  = (const float*)d_in[7];
    float* out = (float*)d_out;

    char* ws = (char*)d_ws;
    const size_t MB = 1 << 20;
    _Float16* Wqt = (_Float16*)(ws);
    _Float16* Wkt = (_Float16*)(ws + MB / 2);
    _Float16* Wvt = (_Float16*)(ws + 2 * (MB / 2));
    _Float16* Pt  = (_Float16*)(ws + 3 * (MB / 2));
    _Float16* Qh  = (_Float16*)(ws + 2 * MB);          // 4MB; Oa reuses this
    _Float16* Kh  = (_Float16*)(ws + 6 * MB);
    _Float16* Vh  = (_Float16*)(ws + 10 * MB);
    _Float16* Qp  = (_Float16*)(ws + 14 * MB);
    _Float16* Kp  = (_Float16*)(ws + 18 * MB);
    _Float16* Vt  = (_Float16*)(ws + 22 * MB);
    _Float16* Oa  = Qh;

    prep_kernel<<<dim3(1024, 7), 256, 0, stream>>>(query, key, value, wq, wk, wv, wp,
                                                   Qh, Kh, Vh, Wqt, Wkt, Wvt, Pt);
    proj3_kernel<<<dim3(32, 8, 3), 256, 0, stream>>>(Qh, Kh, Vh, Wqt, Wkt, Wvt, Qp, Kp, Vt);
    attn_kernel<<<dim3(512), 256, 0, stream>>>(Qp, Kp, Vt, Oa);
    final_gemm<<<dim3(32, 8), 256, 0, stream>>>(Oa, Pt, out, bias);
}

// Round 7
// 135.383 us; speedup vs baseline: 1.0894x; 1.0010x over previous
//
#include <hip/hip_runtime.h>

// MultiHeadAttention: B=2, T=S=2048, D=512, H=8, HS=64
// prep -> proj3 (128x64-col MFMA GEMMs, 3 blk/CU) -> attn (flash, 4 waves =
//   2 q-halves x 2 kv-halves, swapped-QK, static-max exp2(s-12), ones-MFMA
//   rowsum, stride-72 P buffer, 4-buffer K/V ring w/ 2-tile prefetch,
//   1 barrier/tile) -> final GEMM (+bias, f32 out).
// ws (26MB): Wqt|Wkt|Wvt|Pt (512KB ea) | Qh|Kh|Vh (4MB ea; Oa reuses Qh) | Qp|Kp|Vt

typedef float    fx4 __attribute__((ext_vector_type(4)));
typedef _Float16 h8v __attribute__((ext_vector_type(8)));
typedef __fp16   fp16x2 __attribute__((ext_vector_type(2)));
typedef _Float16 h4v __attribute__((ext_vector_type(4)));

#define LOG2E 1.4426950408889634f

typedef const __attribute__((address_space(1))) void* gptr_t;
typedef __attribute__((address_space(3))) void* lptr_t;
__device__ __forceinline__ void gload16(const void* g, void* l) {
    __builtin_amdgcn_global_load_lds((gptr_t)g, (lptr_t)l, 16, 0, 0);
}
#define VMCNT(n) asm volatile("s_waitcnt vmcnt(" #n ")" ::: "memory")
#define LGKMCNT0 asm volatile("s_waitcnt lgkmcnt(0)" ::: "memory")

// ---------------- prep: y=0..2 convert q/k/v to fp16; y=3..6 transpose weights
__global__ __launch_bounds__(256) void prep_kernel(
    const float* __restrict__ q, const float* __restrict__ k, const float* __restrict__ v,
    const float* __restrict__ wq, const float* __restrict__ wk,
    const float* __restrict__ wv, const float* __restrict__ wp,
    _Float16* __restrict__ Qh, _Float16* __restrict__ Kh, _Float16* __restrict__ Vh,
    _Float16* __restrict__ Wqt, _Float16* __restrict__ Wkt,
    _Float16* __restrict__ Wvt, _Float16* __restrict__ Pt)
{
    __shared__ float tile[64 * 65];
    int y = blockIdx.y;
    if (y < 3) {
        const float* src = y == 0 ? q : y == 1 ? k : v;
        _Float16* dst = y == 0 ? Qh : y == 1 ? Kh : Vh;
        int i = (blockIdx.x * 256 + threadIdx.x) * 8;
        float4 f0 = *(const float4*)(src + i);
        float4 f1 = *(const float4*)(src + i + 4);
        h8v hv;
        hv[0] = (_Float16)f0.x; hv[1] = (_Float16)f0.y;
        hv[2] = (_Float16)f0.z; hv[3] = (_Float16)f0.w;
        hv[4] = (_Float16)f1.x; hv[5] = (_Float16)f1.y;
        hv[6] = (_Float16)f1.z; hv[7] = (_Float16)f1.w;
        *(h8v*)(dst + i) = hv;
        return;
    }
    if (blockIdx.x >= 64) return;
    int w = y - 3;
    const float* in = w == 0 ? wq : w == 1 ? wk : w == 2 ? wv : wp;
    _Float16* out = w == 0 ? Wqt : w == 1 ? Wkt : w == 2 ? Wvt : Pt;
    float scale = (w == 0) ? 0.125f * LOG2E : 1.0f;
    const float* src; _Float16* obase; int R0, SI;
    if (w < 3) {                       // [8h][512][64] -> [8h][64][512]
        int h = blockIdx.x >> 3, kt = blockIdx.x & 7;
        src = in + h * 32768 + (kt * 64) * 64; SI = 64;
        obase = out + h * 32768; R0 = kt * 64;
    } else {                           // [512][512] -> [512][512]^T
        int rt = blockIdx.x >> 3, ct = blockIdx.x & 7;
        src = in + (rt * 64) * 512 + ct * 64; SI = 512;
        obase = out + (ct * 64) * 512; R0 = rt * 64;
    }
    int t = threadIdx.x;
    int r = t >> 4, c4 = (t & 15) << 2;
    #pragma unroll
    for (int p = 0; p < 4; ++p) {
        float4 f = *(const float4*)(src + (r + p * 16) * SI + c4);
        tile[(c4 + 0) * 65 + r + p * 16] = f.x;
        tile[(c4 + 1) * 65 + r + p * 16] = f.y;
        tile[(c4 + 2) * 65 + r + p * 16] = f.z;
        tile[(c4 + 3) * 65 + r + p * 16] = f.w;
    }
    __syncthreads();
    int c = t >> 2, seg = (t & 3) << 4;
    h8v h0, h1;
    #pragma unroll
    for (int j = 0; j < 8; ++j) {
        h0[j] = (_Float16)(tile[c * 65 + seg + j] * scale);
        h1[j] = (_Float16)(tile[c * 65 + seg + 8 + j] * scale);
    }
    *(h8v*)(obase + c * 512 + R0 + seg) = h0;
    *(h8v*)(obase + c * 512 + R0 + seg + 8) = h1;
}

// ---------------- proj3: M=4096 N=512(8hx64) K=512, 128x64 tiles, 3 blk/CU -
__global__ __launch_bounds__(256) void proj3_kernel(
    const _Float16* __restrict__ Qh, const _Float16* __restrict__ Kh,
    const _Float16* __restrict__ Vh,
    const _Float16* __restrict__ Wqt, const _Float16* __restrict__ Wkt,
    const _Float16* __restrict__ Wvt,
    _Float16* __restrict__ Qp, _Float16* __restrict__ Kp, _Float16* __restrict__ Vtp)
{
    __shared__ alignas(16) _Float16 As[2][128 * 64];
    __shared__ alignas(16) _Float16 Bs[2][64 * 64];
    const int z = blockIdx.z;
    const _Float16* A  = z == 0 ? Qh : z == 1 ? Kh : Vh;
    const _Float16* Bt = z == 0 ? Wqt : z == 1 ? Wkt : Wvt;
    const int tid = threadIdx.x, lane = tid & 63, wid = tid >> 6;
    const int g = lane >> 4, cl = lane & 15;
    const int brow = blockIdx.x * 128, bc = blockIdx.y;
    const int wr = (wid >> 1) * 64, wc = (wid & 1) * 32;
    fx4 acc[4][2] = {};

    #define STG(ks, buf) do {                                                  \
        _Pragma("unroll")                                                      \
        for (int i = 0; i < 4; ++i) {                                          \
            int ch = (i << 8) + tid; int row = ch >> 3, c16 = ch & 7;          \
            gload16(A + (size_t)(brow + row) * 512 + (ks) * 64 +               \
                        ((c16 ^ (row & 7)) << 3),                              \
                    &As[buf][((i << 8) + (wid << 6)) << 3]);                   \
        }                                                                      \
        _Pragma("unroll")                                                      \
        for (int i = 0; i < 2; ++i) {                                          \
            int ch = (i << 8) + tid; int row = ch >> 3, c16 = ch & 7;          \
            gload16(Bt + (size_t)(bc * 64 + row) * 512 + (ks) * 64 +           \
                        ((c16 ^ (row & 7)) << 3),                              \
                    &Bs[buf][((i << 8) + (wid << 6)) << 3]);                   \
        }                                                                      \
    } while (0)

    #define CMP(buf) do {                                                      \
        _Pragma("unroll")                                                      \
        for (int ko = 0; ko < 2; ++ko) {                                       \
            int kb = (ko << 5) + (g << 3);                                     \
            h8v af[4], bfr[2];                                                 \
            _Pragma("unroll")                                                  \
            for (int mf = 0; mf < 4; ++mf) {                                   \
                int row = wr + mf * 16 + cl;                                   \
                af[mf] = *(h8v*)&As[buf][(row << 6) + (kb ^ ((row & 7) << 3))];\
            }                                                                  \
            _Pragma("unroll")                                                  \
            for (int nf = 0; nf < 2; ++nf) {                                   \
                int row = wc + nf * 16 + cl;                                   \
                bfr[nf] = *(h8v*)&Bs[buf][(row << 6) + (kb ^ ((row & 7) << 3))];\
            }                                                                  \
            __builtin_amdgcn_s_setprio(1);                                     \
            _Pragma("unroll")                                                  \
            for (int mf = 0; mf < 4; ++mf)                                     \
                _Pragma("unroll")                                              \
                for (int nf = 0; nf < 2; ++nf)                                 \
                    acc[mf][nf] = __builtin_amdgcn_mfma_f32_16x16x32_f16(      \
                        af[mf], bfr[nf], acc[mf][nf], 0, 0, 0);                \
            __builtin_amdgcn_s_setprio(0);                                     \
        }                                                                      \
    } while (0)

    STG(0, 0);
    for (int kk = 0; kk < 4; ++kk) {
        STG(2 * kk + 1, 1);
        VMCNT(6);
        __builtin_amdgcn_s_barrier();
        CMP(0);
        __builtin_amdgcn_s_barrier();
        if (kk < 3) { STG(2 * kk + 2, 0); VMCNT(6); } else { VMCNT(0); }
        __builtin_amdgcn_s_barrier();
        CMP(1);
        __builtin_amdgcn_s_barrier();
    }
    #undef STG
    #undef CMP

    if (z != 2) {  // Q/K: [BH][2048][64]
        _Float16* Out = z == 0 ? Qp : Kp;
        #pragma unroll
        for (int mf = 0; mf < 4; ++mf)
            #pragma unroll
            for (int nf = 0; nf < 2; ++nf)
                #pragma unroll
                for (int r = 0; r < 4; ++r) {
                    int grow = brow + wr + mf * 16 + (g << 2) + r;
                    int col = wc + nf * 16 + cl;
                    int b = grow >> 11, n = grow & 2047;
                    Out[((((size_t)(b * 8 + bc)) * 2048 + n) << 6) + col] = (_Float16)acc[mf][nf][r];
                }
    } else {       // V^T: [BH][64][2048]
        #pragma unroll
        for (int mf = 0; mf < 4; ++mf)
            #pragma unroll
            for (int nf = 0; nf < 2; ++nf) {
                int grow = brow + wr + mf * 16 + (g << 2);
                int col = wc + nf * 16 + cl;
                int b = grow >> 11, m = grow & 2047;
                h4v pk;
                #pragma unroll
                for (int r = 0; r < 4; ++r) pk[r] = (_Float16)acc[mf][nf][r];
                *(h4v*)&Vtp[((((size_t)(b * 8 + bc)) * 64 + col) << 11) + m] = pk;
            }
    }
}

// ---------------- final GEMM: Oa fp16 [4096][512] x Pt -> f32 + bias -------
__global__ __launch_bounds__(256) void final_gemm(
    const _Float16* __restrict__ Av, const _Float16* __restrict__ Bt,
    float* __restrict__ O, const float* __restrict__ bias)
{
    __shared__ alignas(16) _Float16 As[2][128 * 64];
    __shared__ alignas(16) _Float16 Bs[2][64 * 64];
    const int tid = threadIdx.x, lane = tid & 63, wid = tid >> 6;
    const int g = lane >> 4, cl = lane & 15;
    const int brow = blockIdx.x * 128, bc = blockIdx.y;
    const int wr = (wid >> 1) * 64, wc = (wid & 1) * 32;
    fx4 acc[4][2] = {};

    #define STG(ks, buf) do {                                                  \
        _Pragma("unroll")                                                      \
        for (int i = 0; i < 4; ++i) {                                          \
            int ch = (i << 8) + tid; int row = ch >> 3, c16 = ch & 7;          \
            gload16(Av + (size_t)(brow + row) * 512 + (ks) * 64 +              \
                        ((c16 ^ (row & 7)) << 3),                              \
                    &As[buf][((i << 8) + (wid << 6)) << 3]);                   \
        }                                                                      \
        _Pragma("unroll")                                                      \
        for (int i = 0; i < 2; ++i) {                                          \
            int ch = (i << 8) + tid; int row = ch >> 3, c16 = ch & 7;          \
            gload16(Bt + (size_t)(bc * 64 + row) * 512 + (ks) * 64 +           \
                        ((c16 ^ (row & 7)) << 3),                              \
                    &Bs[buf][((i << 8) + (wid << 6)) << 3]);                   \
        }                                                                      \
    } while (0)

    #define CMP(buf) do {                                                      \
        _Pragma("unroll")                                                      \
        for (int ko = 0; ko < 2; ++ko) {                                       \
            int kb = (ko << 5) + (g << 3);                                     \
            h8v af[4], bfr[2];                                                 \
            _Pragma("unroll")                                                  \
            for (int mf = 0; mf < 4; ++mf) {                                   \
                int row = wr + mf * 16 + cl;                                   \
                af[mf] = *(h8v*)&As[buf][(row << 6) + (kb ^ ((row & 7) << 3))];\
            }                                                                  \
            _Pragma("unroll")                                                  \
            for (int nf = 0; nf < 2; ++nf) {                                   \
                int row = wc + nf * 16 + cl;                                   \
                bfr[nf] = *(h8v*)&Bs[buf][(row << 6) + (kb ^ ((row & 7) << 3))];\
            }                                                                  \
            __builtin_amdgcn_s_setprio(1);                                     \
            _Pragma("unroll")                                                  \
            for (int mf = 0; mf < 4; ++mf)                                     \
                _Pragma("unroll")                                              \
                for (int nf = 0; nf < 2; ++nf)                                 \
                    acc[mf][nf] = __builtin_amdgcn_mfma_f32_16x16x32_f16(      \
                        af[mf], bfr[nf], acc[mf][nf], 0, 0, 0);                \
            __builtin_amdgcn_s_setprio(0);                                     \
        }                                                                      \
    } while (0)

    STG(0, 0);
    for (int kk = 0; kk < 4; ++kk) {
        STG(2 * kk + 1, 1);
        VMCNT(6);
        __builtin_amdgcn_s_barrier();
        CMP(0);
        __builtin_amdgcn_s_barrier();
        if (kk < 3) { STG(2 * kk + 2, 0); VMCNT(6); } else { VMCNT(0); }
        __builtin_amdgcn_s_barrier();
        CMP(1);
        __builtin_amdgcn_s_barrier();
    }
    #undef STG
    #undef CMP

    #pragma unroll
    for (int mf = 0; mf < 4; ++mf)
        #pragma unroll
        for (int nf = 0; nf < 2; ++nf)
            #pragma unroll
            for (int r = 0; r < 4; ++r) {
                int grow = brow + wr + mf * 16 + (g << 2) + r;
                int col = (bc << 6) + wc + nf * 16 + cl;
                O[((size_t)grow << 9) + col] = acc[mf][nf][r] + bias[col];
            }
}

// ---------------- flash attention: 4 waves = 2 q-halves x 2 kv-halves ------
// Qp/Kp: [BH][2048][64] fp16 (Q pre-scaled by log2e/8). Vg: [BH][64][2048].
// Oa: [B][2048][H][64] fp16.  Q-tile 64/block, grid 512 (2 blk/CU).
// 4-buffer K/V ring, 2-tile-deep prefetch, counted vmcnt(8), ONE barrier per
// tile (ring-4 proof: STAGE(t+2) writes buf (t+2)&3; active CMPs are t,t-1).
// LDS bytes: K 4x8192 @0 | V 4x8192 @32768 | P 4 waves x 2304 @65536 = 74752.
__global__ __launch_bounds__(256) void attn_kernel(
    const _Float16* __restrict__ Qp, const _Float16* __restrict__ Kp,
    const _Float16* __restrict__ Vg, _Float16* __restrict__ Oa)
{
    __shared__ alignas(16) char smem[74752];
    _Float16* KdU = (_Float16*)smem;     // fp16 units: K buf*4096, V 16384+buf*4096
    char* smemc = smem;
    const int tid = threadIdx.x, lane = tid & 63, wid = tid >> 6;
    const int g = lane >> 4, cl = lane & 15;
    const int qh = wid & 1, kvh = wid >> 1;
    int lin = blockIdx.x;                // 0..511
    int xcd = lin & 7, slot = lin >> 3;  // each XCD owns 2 heads (1MB KV, L2-fit)
    int bh = xcd * 2 + (slot & 1);
    int qbase = (slot >> 1) << 6;        // 32 q-tiles of 64
    const size_t hbase = (size_t)bh * (2048 * 64);

    // K-frag offsets: row = kvh*32 + nf*16 + cl, d-chunk ko*32 + g*8
    int kf_off[2][2];
    #pragma unroll
    for (int ko = 0; ko < 2; ++ko)
        #pragma unroll
        for (int nf = 0; nf < 2; ++nf) {
            int row = (kvh << 5) + (nf << 4) + cl;
            kf_off[ko][nf] = (row << 6) + (((ko << 5) + (g << 3)) ^ ((row & 7) << 3));
        }
    // V-frag offsets: row = of*16 + cl, kv-chunk kvh*32 + g*8
    int vf_off[4];
    #pragma unroll
    for (int of = 0; of < 4; ++of) {
        int row = (of << 4) + cl;
        vf_off[of] = (row << 6) + (((kvh << 5) + (g << 3)) ^ ((row & 7) << 3));
    }
    // P buffer: per-wave 32 rows x 72B @65536 (word starts 2(9cl+g): conflict-free)
    const int pw = 65536 + wid * 2304 + cl * 72;

    // ---- stage Q (64x64) into K-buf 0/1 area, read Q as B-fragments
    #pragma unroll
    for (int j = 0; j < 2; ++j) {
        int ch = (j << 8) + tid; int row = ch >> 3, c16 = ch & 7;
        gload16(Qp + hbase + ((size_t)(qbase + row) << 6) + ((c16 ^ (row & 7)) << 3),
                &KdU[((j << 8) + (wid << 6)) << 3]);
    }
    VMCNT(0);
    __builtin_amdgcn_s_barrier();
    h8v qf[2][2];
    #pragma unroll
    for (int mf = 0; mf < 2; ++mf)
        #pragma unroll
        for (int ko = 0; ko < 2; ++ko) {
            int row = (qh << 5) + (mf << 4) + cl;
            qf[mf][ko] = *(h8v*)&KdU[(row << 6) + ((((ko << 5) + (g << 3))) ^ ((row & 7) << 3))];
        }
    LGKMCNT0;
    __builtin_amdgcn_s_barrier();   // all waves read Q before K overwrites

    h8v ones;
    #pragma unroll
    for (int j = 0; j < 8; ++j) ones[j] = (_Float16)1.0f;
    fx4 oacc[2][4] = {};
    fx4 lacc[2] = {};

    #define STAGE_KV(t, buf) do {                                              \
        _Pragma("unroll")                                                      \
        for (int j = 0; j < 2; ++j) {                                          \
            int ch = (j << 8) + tid; int row = ch >> 3, c16 = ch & 7;          \
            int sw = (c16 ^ (row & 7)) << 3;                                   \
            int du = (((j << 8) + (wid << 6)) << 3) + (buf) * 4096;            \
            gload16(Kp + hbase + ((size_t)(((t) << 6) + row) << 6) + sw,       \
                    &KdU[du]);                                                 \
            gload16(Vg + hbase + ((size_t)row << 11) + ((t) << 6) + sw,        \
                    &KdU[du + 16384]);                                         \
        }                                                                      \
    } while (0)

    #define CMP(buf) do {                                                      \
        const int bofs = (buf) * 4096;                                         \
        h8v kf[2][2];                                                          \
        _Pragma("unroll")                                                      \
        for (int ko = 0; ko < 2; ++ko)                                         \
            _Pragma("unroll")                                                  \
            for (int nf = 0; nf < 2; ++nf)                                     \
                kf[ko][nf] = *(h8v*)&KdU[bofs + kf_off[ko][nf]];               \
        fx4 st[2][2];                                                          \
        _Pragma("unroll")                                                      \
        for (int mf = 0; mf < 2; ++mf)                                         \
            _Pragma("unroll")                                                  \
            for (int nf = 0; nf < 2; ++nf)                                     \
                st[mf][nf] = (fx4){-12.f, -12.f, -12.f, -12.f};                \
        __builtin_amdgcn_s_setprio(1);                                         \
        _Pragma("unroll")                                                      \
        for (int ko = 0; ko < 2; ++ko)                                         \
            _Pragma("unroll")                                                  \
            for (int mf = 0; mf < 2; ++mf)                                     \
                _Pragma("unroll")                                              \
                for (int nf = 0; nf < 2; ++nf)                                 \
                    st[mf][nf] = __builtin_amdgcn_mfma_f32_16x16x32_f16(       \
                        kf[ko][nf], qf[mf][ko], st[mf][nf], 0, 0, 0);          \
        __builtin_amdgcn_s_setprio(0);                                         \
        _Pragma("unroll")                                                      \
        for (int mf = 0; mf < 2; ++mf)                                         \
            _Pragma("unroll")                                                  \
            for (int nf = 0; nf < 2; ++nf) {                                   \
                float p0 = __builtin_amdgcn_exp2f(st[mf][nf][0]);              \
                float p1 = __builtin_amdgcn_exp2f(st[mf][nf][1]);              \
                float p2 = __builtin_amdgcn_exp2f(st[mf][nf][2]);              \
                float p3 = __builtin_amdgcn_exp2f(st[mf][nf][3]);              \
                fp16x2 a0 = __builtin_amdgcn_cvt_pkrtz(p0, p1);                \
                fp16x2 a1 = __builtin_amdgcn_cvt_pkrtz(p2, p3);                \
                h4v wv_;                                                       \
                wv_[0] = (_Float16)a0[0]; wv_[1] = (_Float16)a0[1];            \
                wv_[2] = (_Float16)a1[0]; wv_[3] = (_Float16)a1[1];            \
                *(h4v*)(smemc + pw + mf * 1152 + nf * 32 + (g << 3)) = wv_;    \
            }                                                                  \
        h8v pa[2], vf[4];                                                      \
        _Pragma("unroll")                                                      \
        for (int mf = 0; mf < 2; ++mf) {                                       \
            h4v lo = *(h4v*)(smemc + pw + mf * 1152 + (g << 4));               \
            h4v hi = *(h4v*)(smemc + pw + mf * 1152 + (g << 4) + 8);           \
            pa[mf][0] = lo[0]; pa[mf][1] = lo[1];                              \
            pa[mf][2] = lo[2]; pa[mf][3] = lo[3];                              \
            pa[mf][4] = hi[0]; pa[mf][5] = hi[1];                              \
            pa[mf][6] = hi[2]; pa[mf][7] = hi[3];                              \
        }                                                                      \
        _Pragma("unroll")                                                      \
        for (int of = 0; of < 4; ++of)                                         \
            vf[of] = *(h8v*)&KdU[16384 + bofs + vf_off[of]];                   \
        __builtin_amdgcn_s_setprio(1);                                         \
        _Pragma("unroll")                                                      \
        for (int mf = 0; mf < 2; ++mf) {                                       \
            _Pragma("unroll")                                                  \
            for (int of = 0; of < 4; ++of)                                     \
                oacc[mf][of] = __builtin_amdgcn_mfma_f32_16x16x32_f16(         \
                    pa[mf], vf[of], oacc[mf][of], 0, 0, 0);                    \
            lacc[mf] = __builtin_amdgcn_mfma_f32_16x16x32_f16(                 \
                pa[mf], ones, lacc[mf], 0, 0, 0);                              \
        }                                                                      \
        __builtin_amdgcn_s_setprio(0);                                         \
    } while (0)

    STAGE_KV(0, 0);
    STAGE_KV(1, 1);
    for (int t = 0; t < 32; ++t) {
        if (t < 30) {
            STAGE_KV(t + 2, (t + 2) & 3);
            VMCNT(8);                    // tile t landed; t+1,t+2 in flight
        } else if (t == 30) {
            VMCNT(4);
        } else {
            VMCNT(0);
        }
        __builtin_amdgcn_s_barrier();    // single barrier per tile (ring-4)
        CMP(t & 3);
    }
    #undef STAGE_KV
    #undef CMP

    // ---- cross-wave merge (kv halves) + normalize + store
    __syncthreads();                     // all CMP reads done before smem reuse
    int moff = qh * 10240 + lane * 160;  // reuses K/V area (0..40960)
    if (kvh == 1) {
        #pragma unroll
        for (int mf = 0; mf < 2; ++mf)
            #pragma unroll
            for (int of = 0; of < 4; ++of)
                *(fx4*)(smemc + moff + ((mf << 2) + of) * 16) = oacc[mf][of];
        *(fx4*)(smemc + moff + 128) = lacc[0];
        *(fx4*)(smemc + moff + 144) = lacc[1];
    }
    __syncthreads();
    if (kvh == 0) {
        #pragma unroll
        for (int mf = 0; mf < 2; ++mf)
            #pragma unroll
            for (int of = 0; of < 4; ++of)
                oacc[mf][of] += *(fx4*)(smemc + moff + ((mf << 2) + of) * 16);
        lacc[0] += *(fx4*)(smemc + moff + 128);
        lacc[1] += *(fx4*)(smemc + moff + 144);
        int b = bh >> 3, h = bh & 7;
        #pragma unroll
        for (int mf = 0; mf < 2; ++mf)
            #pragma unroll
            for (int r = 0; r < 4; ++r) {
                float inv = 1.0f / lacc[mf][r];
                int n = qbase + (qh << 5) + (mf << 4) + (g << 2) + r;
                size_t base = ((((size_t)b * 2048 + n) * 8) + h) << 6;
                #pragma unroll
                for (int of = 0; of < 4; ++of)
                    Oa[base + (of << 4) + cl] = (_Float16)(oacc[mf][of][r] * inv);
            }
    }
}

extern "C" void kernel_launch(void* const* d_in, const int* in_sizes, int n_in,
                              void* d_out, int out_size, void* d_ws, size_t ws_size,
                              hipStream_t stream) {
    const float* query = (const float*)d_in[0];
    const float* key   = (const float*)d_in[1];
    const float* value = (const float*)d_in[2];
    const float* wq    = (const float*)d_in[3];
    const float* wk    = (const float*)d_in[4];
    const float* wv    = (const float*)d_in[5];
    const float* wp    = (const float*)d_in[6];
    const float* bias  = (const float*)d_in[7];
    float* out = (float*)d_out;

    char* ws = (char*)d_ws;
    const size_t MB = 1 << 20;
    _Float16* Wqt = (_Float16*)(ws);
    _Float16* Wkt = (_Float16*)(ws + MB / 2);
    _Float16* Wvt = (_Float16*)(ws + 2 * (MB / 2));
    _Float16* Pt  = (_Float16*)(ws + 3 * (MB / 2));
    _Float16* Qh  = (_Float16*)(ws + 2 * MB);          // 4MB; Oa reuses this
    _Float16* Kh  = (_Float16*)(ws + 6 * MB);
    _Float16* Vh  = (_Float16*)(ws + 10 * MB);
    _Float16* Qp  = (_Float16*)(ws + 14 * MB);
    _Float16* Kp  = (_Float16*)(ws + 18 * MB);
    _Float16* Vt  = (_Float16*)(ws + 22 * MB);
    _Float16* Oa  = Qh;

    prep_kernel<<<dim3(1024, 7), 256, 0, stream>>>(query, key, value, wq, wk, wv, wp,
                                                   Qh, Kh, Vh, Wqt, Wkt, Wvt, Pt);
    proj3_kernel<<<dim3(32, 8, 3), 256, 0, stream>>>(Qh, Kh, Vh, Wqt, Wkt, Wvt, Qp, Kp, Vt);
    attn_kernel<<<dim3(512), 256, 0, stream>>>(Qp, Kp, Vt, Oa);
    final_gemm<<<dim3(32, 8), 256, 0, stream>>>(Oa, Pt, out, bias);
}